// Round 2
// baseline (268.538 us; speedup 1.0000x reference)
//
#include <hip/hip_runtime.h>
#include <math.h>

#define BB 32
#define MM 10
#define NNODES 1010
#define DD 128
#define RPB 32                          // node rows per block in k_main
#define NG ((NNODES + RPB - 1) / RPB)   // 32

// ---------------------------------------------------------------------------
// Kernel 1: per-(b,m) agent-side small embeddings, K split 4-ways (512 thr).
//   thread t -> (d = t&127, q = t>>7); each q handles K/4 of every dot,
//   LDS tree-reduce. 8 waves/block to hide gather latency.
// ---------------------------------------------------------------------------
__global__ __launch_bounds__(512) void k_agents(
    const float* __restrict__ locs,      // (B, 1010, 2)
    const float* __restrict__ capacity,  // (B, 10)
    const float* __restrict__ speed,     // (B, 10)
    const float* __restrict__ W_depot,   // (128, 2)
    const float* __restrict__ W_posproj, // (128, 128)
    const float* __restrict__ alpha,     // (1,)
    const float* __restrict__ W_agents,  // (128, 4)
    const float* __restrict__ W_da,      // (128, 256)
    const float* __restrict__ W_pref,    // (128, 1)
    const float* __restrict__ W_final,   // (128, 384)
    float* __restrict__ out_nodes,       // (B, 1010, 128)
    float* __restrict__ ws_daWd,         // (B, 10, 128)
    float* __restrict__ ws_vpref)        // (128,)
{
    const int b = blockIdx.x / MM;
    const int m = blockIdx.x % MM;
    const int t = threadIdx.x;
    const int d = t & (DD - 1);
    const int q = t >> 7;   // 0..3

    __shared__ float pe_s[DD];
    __shared__ float dep_s[DD];
    __shared__ float ag_s[DD];
    __shared__ float da_s[DD];
    __shared__ float part[4][DD];

    if (q == 0) {
        const int i = d >> 1;
        const float div = expf((float)(2 * i) * (-logf(10000.0f) / (float)DD));
        const float ang = (float)m * div;
        pe_s[d] = (d & 1) ? cosf(ang) : sinf(ang);
    }
    __syncthreads();

    // partial: dot(pe, W_posproj[d, q*32 : q*32+32])
    float pp = 0.0f;
    {
        const float4* wp  = (const float4*)(W_posproj + (size_t)d * DD + q * 32);
        const float4* pe4 = (const float4*)(pe_s + q * 32);
        #pragma unroll
        for (int k4 = 0; k4 < 8; ++k4) {
            const float4 w = wp[k4], p = pe4[k4];
            pp = fmaf(w.x, p.x, fmaf(w.y, p.y, fmaf(w.z, p.z, fmaf(w.w, p.w, pp))));
        }
    }
    part[q][d] = pp;
    __syncthreads();

    if (q == 0) {
        const float ppf = part[0][d] + part[1][d] + part[2][d] + part[3][d];
        const float lx = locs[((size_t)b * NNODES + m) * 2 + 0];
        const float ly = locs[((size_t)b * NNODES + m) * 2 + 1];
        const float dep = fmaf(lx, W_depot[d * 2 + 0],
                          fmaf(ly, W_depot[d * 2 + 1], alpha[0] * ppf));
        const float cap = capacity[b * MM + m] * (1.0f / 40.0f);
        const float spd = speed[b * MM + m];
        const float ag = fmaf(lx, W_agents[d * 4 + 0],
                         fmaf(ly, W_agents[d * 4 + 1],
                         fmaf(cap, W_agents[d * 4 + 2],
                              spd * W_agents[d * 4 + 3])));
        out_nodes[((size_t)b * NNODES + m) * DD + d] = ag;
        dep_s[d] = dep;
        ag_s[d] = ag;
    }
    __syncthreads();

    // partial: dot(concat(dep, ag), W_da[d, q*64 : q*64+64])
    float da = 0.0f;
    {
        const float4* s4  = (const float4*)((q < 2) ? (dep_s + q * 64)
                                                    : (ag_s + (q - 2) * 64));
        const float4* wda = (const float4*)(W_da + (size_t)d * 2 * DD + q * 64);
        #pragma unroll
        for (int k4 = 0; k4 < 16; ++k4) {
            const float4 w = wda[k4], p = s4[k4];
            da = fmaf(w.x, p.x, fmaf(w.y, p.y, fmaf(w.z, p.z, fmaf(w.w, p.w, da))));
        }
    }
    part[q][d] = da;
    __syncthreads();
    if (q == 0) da_s[d] = part[0][d] + part[1][d] + part[2][d] + part[3][d];
    __syncthreads();

    // partial: dot(da, W_final[d, 256+q*32 : 256+q*32+32])
    float dw = 0.0f;
    {
        const float4* wfd = (const float4*)(W_final + (size_t)d * 3 * DD + 2 * DD + q * 32);
        const float4* s4  = (const float4*)(da_s + q * 32);
        #pragma unroll
        for (int k4 = 0; k4 < 8; ++k4) {
            const float4 w = wfd[k4], p = s4[k4];
            dw = fmaf(w.x, p.x, fmaf(w.y, p.y, fmaf(w.z, p.z, fmaf(w.w, p.w, dw))));
        }
    }
    part[q][d] = dw;
    __syncthreads();
    if (q == 0)
        ws_daWd[(b * MM + m) * DD + d] = part[0][d] + part[1][d] + part[2][d] + part[3][d];

    // v_pref (once, block 0, independent of LDS above)
    if (blockIdx.x == 0 && q == 3) {
        float vp = 0.0f;
        const float4* wfp = (const float4*)(W_final + (size_t)d * 3 * DD + DD);
        const float4* prf = (const float4*)W_pref;
        #pragma unroll
        for (int k4 = 0; k4 < DD / 4; ++k4) {
            const float4 w = wfp[k4], p = prf[k4];
            vp = fmaf(w.x, p.x, fmaf(w.y, p.y, fmaf(w.z, p.z, fmaf(w.w, p.w, vp))));
        }
        ws_vpref[d] = vp;
    }
}

// ---------------------------------------------------------------------------
// Kernel 2: 32-node x 128-col tile per block, 256 threads.
//   phase A: client embeddings -> out_nodes + LDS rows (thread = (d, half))
//   phase B: thread = (colgroup c of 4 cols, subgroup s of 4 rows);
//            per k4: 1 LDS float4 / row feeds 16 fma -> 4x fewer ds_reads
//   phase C: fused combined-embedding expansion, float4 stores, mm-outer
// ---------------------------------------------------------------------------
__global__ __launch_bounds__(256) void k_main(
    const float* __restrict__ locs,      // (B, 1010, 2)
    const float* __restrict__ demand,    // (B, 1, 1010)
    const float* __restrict__ pref,      // (B, 10, 1010)
    const float* __restrict__ W_clients, // (128, 5)
    const float* __restrict__ W_final,   // (128, 384)
    const float* __restrict__ ws_daWd,   // (B, 10, 128)
    const float* __restrict__ ws_vpref,  // (128,)
    float* __restrict__ out_nodes,       // (B, 1010, 128)
    float* __restrict__ out_comb)        // (B, 10, 1010, 128)
{
    const int g = blockIdx.x;
    const int b = blockIdx.y;
    const int t = threadIdx.x;
    const int n0 = g * RPB;

    __shared__ float rows[RPB][DD];      // 16 KB
    __shared__ float feat[RPB][5];
    __shared__ float pref_s[MM][RPB];    // 1.25 KB

    // per-node client scalar features (threads 0..31)
    if (t < RPB) {
        const int node = n0 + t;
        if (node < NNODES && node >= MM) {
            const float cx = locs[((size_t)b * NNODES + node) * 2 + 0];
            const float cy = locs[((size_t)b * NNODES + node) * 2 + 1];
            const float d0x = locs[((size_t)b * NNODES + 0) * 2 + 0];
            const float d0y = locs[((size_t)b * NNODES + 0) * 2 + 1];
            const float dx = cx - d0x;
            const float dy = cy - d0y;
            feat[t][0] = cx;
            feat[t][1] = cy;
            feat[t][2] = demand[(size_t)b * NNODES + node] * (1.0f / 40.0f);
            feat[t][3] = sqrtf(fmaf(dx, dx, dy * dy));
            feat[t][4] = atan2f(dy, dx);
        }
    }
    // pref tile -> LDS
    for (int idx = t; idx < MM * RPB; idx += 256) {
        const int mm = idx >> 5;
        const int rr = idx & 31;
        const int node = n0 + rr;
        pref_s[mm][rr] = (node < NNODES)
            ? pref[(size_t)(b * MM + mm) * NNODES + node] : 0.0f;
    }
    __syncthreads();

    // phase A: rows[r][d] = nodes_embedding value
    {
        const int d = t & (DD - 1);
        const int h = t >> 7;            // 0/1: rows h*16 .. h*16+15
        const float wc0 = W_clients[d * 5 + 0];
        const float wc1 = W_clients[d * 5 + 1];
        const float wc2 = W_clients[d * 5 + 2];
        const float wc3 = W_clients[d * 5 + 3];
        const float wc4 = W_clients[d * 5 + 4];
        #pragma unroll
        for (int i = 0; i < RPB / 2; ++i) {
            const int r = h * (RPB / 2) + i;
            const int node = n0 + r;
            float val = 0.0f;
            if (node < NNODES) {
                if (node < MM) {
                    val = out_nodes[((size_t)b * NNODES + node) * DD + d];
                } else {
                    val = fmaf(feat[r][0], wc0,
                          fmaf(feat[r][1], wc1,
                          fmaf(feat[r][2], wc2,
                          fmaf(feat[r][3], wc3,
                               feat[r][4] * wc4))));
                    out_nodes[((size_t)b * NNODES + node) * DD + d] = val;
                }
            }
            rows[r][d] = val;
        }
    }
    __syncthreads();

    // phase B: thread (c = t&31 -> cols 4c..4c+3, s = t>>5 -> rows 4s..4s+3)
    const int c = t & 31;
    const int s = t >> 5;
    const int col = c * 4;
    float4 acc[4];
    #pragma unroll
    for (int j = 0; j < 4; ++j) acc[j] = make_float4(0.f, 0.f, 0.f, 0.f);

    {
        const float* w_base = W_final + (size_t)col * 3 * DD;  // row stride 384
        #pragma unroll 4
        for (int k4 = 0; k4 < DD / 4; ++k4) {
            float4 w[4];
            #pragma unroll
            for (int i = 0; i < 4; ++i)
                w[i] = *(const float4*)(w_base + (size_t)i * 3 * DD + k4 * 4);
            #pragma unroll
            for (int j = 0; j < 4; ++j) {
                const float4 x = *(const float4*)&rows[s * 4 + j][k4 * 4];
                acc[j].x = fmaf(x.x, w[0].x, fmaf(x.y, w[0].y,
                           fmaf(x.z, w[0].z, fmaf(x.w, w[0].w, acc[j].x))));
                acc[j].y = fmaf(x.x, w[1].x, fmaf(x.y, w[1].y,
                           fmaf(x.z, w[1].z, fmaf(x.w, w[1].w, acc[j].y))));
                acc[j].z = fmaf(x.x, w[2].x, fmaf(x.y, w[2].y,
                           fmaf(x.z, w[2].z, fmaf(x.w, w[2].w, acc[j].z))));
                acc[j].w = fmaf(x.x, w[3].x, fmaf(x.y, w[3].y,
                           fmaf(x.z, w[3].z, fmaf(x.w, w[3].w, acc[j].w))));
            }
        }
    }

    // phase C: combined = nwn + pref * v_pref + daWd, float4 stores
    const float4 vp = *(const float4*)(ws_vpref + col);
    float4 dawd[MM];
    #pragma unroll
    for (int mm = 0; mm < MM; ++mm)
        dawd[mm] = *(const float4*)(ws_daWd + (size_t)(b * MM + mm) * DD + col);

    #pragma unroll
    for (int mm = 0; mm < MM; ++mm) {
        #pragma unroll
        for (int j = 0; j < 4; ++j) {
            const int node = n0 + s * 4 + j;
            if (node >= NNODES) continue;
            const float pr = pref_s[mm][s * 4 + j];
            float4 o;
            o.x = fmaf(pr, vp.x, acc[j].x + dawd[mm].x);
            o.y = fmaf(pr, vp.y, acc[j].y + dawd[mm].y);
            o.z = fmaf(pr, vp.z, acc[j].z + dawd[mm].z);
            o.w = fmaf(pr, vp.w, acc[j].w + dawd[mm].w);
            *(float4*)(out_comb +
                ((size_t)(b * MM + mm) * NNODES + node) * DD + col) = o;
        }
    }
}

extern "C" void kernel_launch(void* const* d_in, const int* in_sizes, int n_in,
                              void* d_out, int out_size, void* d_ws, size_t ws_size,
                              hipStream_t stream) {
    const float* locs        = (const float*)d_in[0];
    const float* capacity    = (const float*)d_in[1];
    const float* speed       = (const float*)d_in[2];
    const float* demand      = (const float*)d_in[3];
    const float* agents_pref = (const float*)d_in[4];
    // d_in[5] action_mask: only its shape is used by the reference
    const float* W_depot     = (const float*)d_in[6];
    const float* W_posproj   = (const float*)d_in[7];
    const float* alpha       = (const float*)d_in[8];
    const float* W_agents    = (const float*)d_in[9];
    const float* W_da        = (const float*)d_in[10];
    const float* W_clients   = (const float*)d_in[11];
    const float* W_pref      = (const float*)d_in[12];
    const float* W_final     = (const float*)d_in[13];

    float* out_nodes = (float*)d_out;                         // 32*1010*128
    float* out_comb  = out_nodes + (size_t)BB * NNODES * DD;  // 32*10*1010*128

    float* ws_daWd  = (float*)d_ws;                 // 32*10*128 floats
    float* ws_vpref = ws_daWd + BB * MM * DD;       // 128 floats

    k_agents<<<dim3(BB * MM), 512, 0, stream>>>(
        locs, capacity, speed, W_depot, W_posproj, alpha, W_agents,
        W_da, W_pref, W_final, out_nodes, ws_daWd, ws_vpref);

    k_main<<<dim3(NG, BB), 256, 0, stream>>>(
        locs, demand, agents_pref, W_clients, W_final,
        ws_daWd, ws_vpref, out_nodes, out_comb);
}

// Round 3
// 234.292 us; speedup vs baseline: 1.1462x; 1.1462x over previous
//
#include <hip/hip_runtime.h>
#include <math.h>

#define BB 32
#define MM 10
#define NNODES 1010
#define DD 128
#define RPB 32                          // node rows per block in k_main
#define NG 32                           // ceil(1010/32)

// ---------------------------------------------------------------------------
// Prep kernel (43 blocks x 256 thr):
//   blocks  0..15 : WnT[k][d] = W_final[d][k],  WdT[k][d] = W_final[d][256+k]
//   blocks 16..31 : W_daT[k][d] = W_da[d][k]           (k in [0,256))
//   block  32     : v_pref[d] = dot(W_final[d,128:256], W_pref)
//   blocks 33..42 : peproj[m][d] = dot(pe[m,:], W_posproj[d,:])  (b-invariant!)
// ---------------------------------------------------------------------------
__global__ __launch_bounds__(256) void k_prep(
    const float* __restrict__ W_posproj, // (128,128)
    const float* __restrict__ W_da,      // (128,256)
    const float* __restrict__ W_pref,    // (128,1)
    const float* __restrict__ W_final,   // (128,384)
    float* __restrict__ wnT,             // (128,128)
    float* __restrict__ wdT,             // (128,128)
    float* __restrict__ wdaT,            // (256,128)
    float* __restrict__ vpref,           // (128,)
    float* __restrict__ peproj)          // (10,128)
{
    const int bk = blockIdx.x;
    const int t = threadIdx.x;
    const int d = t & (DD - 1);
    const int h = t >> 7;   // 0/1

    if (bk < 16) {
        #pragma unroll
        for (int kk = 0; kk < 4; ++kk) {
            const int k = bk * 8 + h * 4 + kk;
            wnT[k * DD + d] = W_final[(size_t)d * 384 + k];
            wdT[k * DD + d] = W_final[(size_t)d * 384 + 256 + k];
        }
    } else if (bk < 32) {
        #pragma unroll
        for (int kk = 0; kk < 8; ++kk) {
            const int k = (bk - 16) * 16 + h * 8 + kk;
            wdaT[k * DD + d] = W_da[(size_t)d * 256 + k];
        }
    } else if (bk == 32) {
        if (t < DD) {
            float vp = 0.0f;
            const float4* w = (const float4*)(W_final + (size_t)d * 384 + DD);
            const float4* p = (const float4*)W_pref;
            #pragma unroll
            for (int k4 = 0; k4 < 32; ++k4) {
                const float4 a = w[k4], b = p[k4];
                vp = fmaf(a.x, b.x, fmaf(a.y, b.y, fmaf(a.z, b.z, fmaf(a.w, b.w, vp))));
            }
            vpref[d] = vp;
        }
    } else {
        const int m = bk - 33;
        __shared__ float pe_s[DD];
        if (t < DD) {
            const int i = d >> 1;
            const float div = expf((float)(2 * i) * (-logf(10000.0f) / (float)DD));
            const float ang = (float)m * div;
            pe_s[d] = (d & 1) ? cosf(ang) : sinf(ang);
        }
        __syncthreads();
        if (t < DD) {
            float pp = 0.0f;
            const float4* w = (const float4*)(W_posproj + (size_t)d * DD);
            const float4* p = (const float4*)pe_s;
            #pragma unroll
            for (int k4 = 0; k4 < 32; ++k4) {
                const float4 a = w[k4], b = p[k4];
                pp = fmaf(a.x, b.x, fmaf(a.y, b.y, fmaf(a.z, b.z, fmaf(a.w, b.w, pp))));
            }
            peproj[m * DD + d] = pp;
        }
    }
}

// ---------------------------------------------------------------------------
// Kernel 2: per-(b,m) agent embeddings via broadcast-gemv on transposed W.
//   256 thr: d = t&127, h = t>>7 splits each K-loop in half.
// ---------------------------------------------------------------------------
__global__ __launch_bounds__(256) void k_agents(
    const float* __restrict__ locs,      // (B, 1010, 2)
    const float* __restrict__ capacity,  // (B, 10)
    const float* __restrict__ speed,     // (B, 10)
    const float* __restrict__ W_depot,   // (128, 2)
    const float* __restrict__ alpha,     // (1,)
    const float* __restrict__ W_agents,  // (128, 4)
    const float* __restrict__ wdaT,      // (256, 128)
    const float* __restrict__ wdT,       // (128, 128)
    const float* __restrict__ peproj,    // (10, 128)
    float* __restrict__ out_nodes,       // (B, 1010, 128)
    float* __restrict__ ws_daWd)         // (B, 10, 128)
{
    const int b = blockIdx.x / MM;
    const int m = blockIdx.x % MM;
    const int t = threadIdx.x;
    const int d = t & (DD - 1);
    const int h = t >> 7;

    __shared__ float cat_s[2 * DD];      // [dep | ag]
    __shared__ float da_s[DD];
    __shared__ float part[2][DD];

    if (h == 0) {
        const float lx = locs[((size_t)b * NNODES + m) * 2 + 0];
        const float ly = locs[((size_t)b * NNODES + m) * 2 + 1];
        const float dep = fmaf(lx, W_depot[d * 2 + 0],
                          fmaf(ly, W_depot[d * 2 + 1],
                               alpha[0] * peproj[m * DD + d]));
        const float cap = capacity[b * MM + m] * (1.0f / 40.0f);
        const float spd = speed[b * MM + m];
        const float ag = fmaf(lx, W_agents[d * 4 + 0],
                         fmaf(ly, W_agents[d * 4 + 1],
                         fmaf(cap, W_agents[d * 4 + 2],
                              spd * W_agents[d * 4 + 3])));
        out_nodes[((size_t)b * NNODES + m) * DD + d] = ag;
        cat_s[d] = dep;
        cat_s[DD + d] = ag;
    }
    __syncthreads();

    // da[d] = sum_k cat[k] * W_daT[k][d]   (half handles 128 k's)
    {
        float a0 = 0.f, a1 = 0.f, a2 = 0.f, a3 = 0.f;
        const float* wp = wdaT + (size_t)(h * DD) * DD + d;
        const float* cp = cat_s + h * DD;
        #pragma unroll 8
        for (int k = 0; k < DD; k += 4) {
            a0 = fmaf(cp[k + 0], wp[(size_t)(k + 0) * DD], a0);
            a1 = fmaf(cp[k + 1], wp[(size_t)(k + 1) * DD], a1);
            a2 = fmaf(cp[k + 2], wp[(size_t)(k + 2) * DD], a2);
            a3 = fmaf(cp[k + 3], wp[(size_t)(k + 3) * DD], a3);
        }
        part[h][d] = (a0 + a1) + (a2 + a3);
    }
    __syncthreads();
    if (h == 0) da_s[d] = part[0][d] + part[1][d];
    __syncthreads();

    // daWd[d] = sum_k da[k] * WdT[k][d]   (half handles 64 k's)
    {
        float a0 = 0.f, a1 = 0.f, a2 = 0.f, a3 = 0.f;
        const float* wp = wdT + (size_t)(h * 64) * DD + d;
        const float* cp = da_s + h * 64;
        #pragma unroll 4
        for (int k = 0; k < 64; k += 4) {
            a0 = fmaf(cp[k + 0], wp[(size_t)(k + 0) * DD], a0);
            a1 = fmaf(cp[k + 1], wp[(size_t)(k + 1) * DD], a1);
            a2 = fmaf(cp[k + 2], wp[(size_t)(k + 2) * DD], a2);
            a3 = fmaf(cp[k + 3], wp[(size_t)(k + 3) * DD], a3);
        }
        part[h][d] = (a0 + a1) + (a2 + a3);
    }
    __syncthreads();
    if (h == 0)
        ws_daWd[(b * MM + m) * DD + d] = part[0][d] + part[1][d];
}

// ---------------------------------------------------------------------------
// Kernel 3: 32-node x 128-col tile per block, 256 threads.
//   phase A: client embeddings -> out_nodes + LDS rows
//   phase B: acc[j] += rows(bcast LDS f4) x WnT(coalesced global f4)
//   phase C: fused combined-embedding expansion, float4 stores
// ---------------------------------------------------------------------------
__global__ __launch_bounds__(256) void k_main(
    const float* __restrict__ locs,      // (B, 1010, 2)
    const float* __restrict__ demand,    // (B, 1, 1010)
    const float* __restrict__ pref,      // (B, 10, 1010)
    const float* __restrict__ W_clients, // (128, 5)
    const float* __restrict__ wnT,       // (128, 128)
    const float* __restrict__ ws_daWd,   // (B, 10, 128)
    const float* __restrict__ ws_vpref,  // (128,)
    float* __restrict__ out_nodes,       // (B, 1010, 128)
    float* __restrict__ out_comb)        // (B, 10, 1010, 128)
{
    const int g = blockIdx.x;
    const int b = blockIdx.y;
    const int t = threadIdx.x;
    const int n0 = g * RPB;

    __shared__ float rows[RPB][DD];      // 16 KB
    __shared__ float feat[RPB][5];
    __shared__ float pref_s[MM][RPB];

    if (t < RPB) {
        const int node = n0 + t;
        if (node < NNODES && node >= MM) {
            const float cx = locs[((size_t)b * NNODES + node) * 2 + 0];
            const float cy = locs[((size_t)b * NNODES + node) * 2 + 1];
            const float d0x = locs[((size_t)b * NNODES + 0) * 2 + 0];
            const float d0y = locs[((size_t)b * NNODES + 0) * 2 + 1];
            const float dx = cx - d0x;
            const float dy = cy - d0y;
            feat[t][0] = cx;
            feat[t][1] = cy;
            feat[t][2] = demand[(size_t)b * NNODES + node] * (1.0f / 40.0f);
            feat[t][3] = sqrtf(fmaf(dx, dx, dy * dy));
            feat[t][4] = atan2f(dy, dx);
        }
    }
    for (int idx = t; idx < MM * RPB; idx += 256) {
        const int mm = idx >> 5;
        const int rr = idx & 31;
        const int node = n0 + rr;
        pref_s[mm][rr] = (node < NNODES)
            ? pref[(size_t)(b * MM + mm) * NNODES + node] : 0.0f;
    }
    __syncthreads();

    // phase A
    {
        const int d = t & (DD - 1);
        const int h = t >> 7;
        const float wc0 = W_clients[d * 5 + 0];
        const float wc1 = W_clients[d * 5 + 1];
        const float wc2 = W_clients[d * 5 + 2];
        const float wc3 = W_clients[d * 5 + 3];
        const float wc4 = W_clients[d * 5 + 4];
        #pragma unroll
        for (int i = 0; i < RPB / 2; ++i) {
            const int r = h * (RPB / 2) + i;
            const int node = n0 + r;
            float val = 0.0f;
            if (node < NNODES) {
                if (node < MM) {
                    val = out_nodes[((size_t)b * NNODES + node) * DD + d];
                } else {
                    val = fmaf(feat[r][0], wc0,
                          fmaf(feat[r][1], wc1,
                          fmaf(feat[r][2], wc2,
                          fmaf(feat[r][3], wc3,
                               feat[r][4] * wc4))));
                    out_nodes[((size_t)b * NNODES + node) * DD + d] = val;
                }
            }
            rows[r][d] = val;
        }
    }
    __syncthreads();

    // phase B: thread (c = t&31 -> cols 4c..4c+3, s = t>>5 -> rows 4s..4s+3)
    const int c = t & 31;
    const int s = t >> 5;
    const int col = c * 4;
    float4 acc[4];
    #pragma unroll
    for (int j = 0; j < 4; ++j) acc[j] = make_float4(0.f, 0.f, 0.f, 0.f);

    {
        const float* wt = wnT + col;
        #pragma unroll 2
        for (int k4 = 0; k4 < DD / 4; ++k4) {
            const float4 w0 = *(const float4*)(wt + (size_t)(k4 * 4 + 0) * DD);
            const float4 w1 = *(const float4*)(wt + (size_t)(k4 * 4 + 1) * DD);
            const float4 w2 = *(const float4*)(wt + (size_t)(k4 * 4 + 2) * DD);
            const float4 w3 = *(const float4*)(wt + (size_t)(k4 * 4 + 3) * DD);
            #pragma unroll
            for (int j = 0; j < 4; ++j) {
                const float4 x = *(const float4*)&rows[s * 4 + j][k4 * 4];
                acc[j].x = fmaf(x.x, w0.x, fmaf(x.y, w1.x,
                           fmaf(x.z, w2.x, fmaf(x.w, w3.x, acc[j].x))));
                acc[j].y = fmaf(x.x, w0.y, fmaf(x.y, w1.y,
                           fmaf(x.z, w2.y, fmaf(x.w, w3.y, acc[j].y))));
                acc[j].z = fmaf(x.x, w0.z, fmaf(x.y, w1.z,
                           fmaf(x.z, w2.z, fmaf(x.w, w3.z, acc[j].z))));
                acc[j].w = fmaf(x.x, w0.w, fmaf(x.y, w1.w,
                           fmaf(x.z, w2.w, fmaf(x.w, w3.w, acc[j].w))));
            }
        }
    }

    // phase C
    const float4 vp = *(const float4*)(ws_vpref + col);
    float4 dawd[MM];
    #pragma unroll
    for (int mm = 0; mm < MM; ++mm)
        dawd[mm] = *(const float4*)(ws_daWd + (size_t)(b * MM + mm) * DD + col);

    #pragma unroll
    for (int mm = 0; mm < MM; ++mm) {
        #pragma unroll
        for (int j = 0; j < 4; ++j) {
            const int node = n0 + s * 4 + j;
            if (node >= NNODES) continue;
            const float pr = pref_s[mm][s * 4 + j];
            float4 o;
            o.x = fmaf(pr, vp.x, acc[j].x + dawd[mm].x);
            o.y = fmaf(pr, vp.y, acc[j].y + dawd[mm].y);
            o.z = fmaf(pr, vp.z, acc[j].z + dawd[mm].z);
            o.w = fmaf(pr, vp.w, acc[j].w + dawd[mm].w);
            *(float4*)(out_comb +
                ((size_t)(b * MM + mm) * NNODES + node) * DD + col) = o;
        }
    }
}

extern "C" void kernel_launch(void* const* d_in, const int* in_sizes, int n_in,
                              void* d_out, int out_size, void* d_ws, size_t ws_size,
                              hipStream_t stream) {
    const float* locs        = (const float*)d_in[0];
    const float* capacity    = (const float*)d_in[1];
    const float* speed       = (const float*)d_in[2];
    const float* demand      = (const float*)d_in[3];
    const float* agents_pref = (const float*)d_in[4];
    // d_in[5] action_mask: only its shape is used by the reference
    const float* W_depot     = (const float*)d_in[6];
    const float* W_posproj   = (const float*)d_in[7];
    const float* alpha       = (const float*)d_in[8];
    const float* W_agents    = (const float*)d_in[9];
    const float* W_da        = (const float*)d_in[10];
    const float* W_clients   = (const float*)d_in[11];
    const float* W_pref      = (const float*)d_in[12];
    const float* W_final     = (const float*)d_in[13];

    float* out_nodes = (float*)d_out;                         // 32*1010*128
    float* out_comb  = out_nodes + (size_t)BB * NNODES * DD;  // 32*10*1010*128

    float* ws_daWd  = (float*)d_ws;                     // 40960
    float* ws_vpref = ws_daWd + BB * MM * DD;           // 128
    float* ws_pepj  = ws_vpref + DD;                    // 1280
    float* ws_wnT   = ws_pepj + MM * DD;                // 16384
    float* ws_wdT   = ws_wnT + DD * DD;                 // 16384
    float* ws_wdaT  = ws_wdT + DD * DD;                 // 32768

    k_prep<<<dim3(43), 256, 0, stream>>>(
        W_posproj, W_da, W_pref, W_final,
        ws_wnT, ws_wdT, ws_wdaT, ws_vpref, ws_pepj);

    k_agents<<<dim3(BB * MM), 256, 0, stream>>>(
        locs, capacity, speed, W_depot, alpha, W_agents,
        ws_wdaT, ws_wdT, ws_pepj, out_nodes, ws_daWd);

    k_main<<<dim3(NG, BB), 256, 0, stream>>>(
        locs, demand, agents_pref, W_clients, ws_wnT,
        ws_daWd, ws_vpref, out_nodes, out_comb);
}